// Round 10
// baseline (424.872 us; speedup 1.0000x reference)
//
#include <hip/hip_runtime.h>
#include <math.h>
#include <stdint.h>

#define N_NODES 100000
#define N_EDGES 1600000
#define IN_DIM  256
#define HID     128
#define EPS_C   0.3f

// bucket partition for write-local CSR processing
#define NPB      256              // nodes per bucket (dst >> 8)
#define NBKT     391              // ceil(N_NODES / NPB)
#define BCAP     5504             // per-bucket edge capacity (mean 4096, +22 sigma)
#define S1_CHUNK 4096             // edges per partition block (391 blocks)
#define S1_BLOCKS 391             // ceil(N_EDGES / S1_CHUNK)
#define GC(b)    ((b) * 16)       // gcur padded: 1 counter per 64B line

// packed edge word: bits [16:0] = src (100000 < 2^17), bits [24:17] = dst & 255
#define PK_SRC(p)  ((p) & 0x1FFFF)
#define PK_LI(p)   ((p) >> 17)

typedef __attribute__((ext_vector_type(8))) __bf16 bf16x8;
typedef __attribute__((ext_vector_type(4))) float  f32x4;
typedef __attribute__((ext_vector_type(8))) unsigned short ushort8;

static __device__ __forceinline__ unsigned short f2bf(float f) {
    unsigned u = __float_as_uint(f);
    unsigned r = (u + 0x7fffu + ((u >> 16) & 1u)) >> 16;
    return (unsigned short)r;
}
static __device__ __forceinline__ float bf2f(unsigned short s) {
    return __uint_as_float((unsigned)s << 16);
}
// branch-free tanh: 1 - 2/(exp2(2x*log2e)+1); correct limits at +-inf
static __device__ __forceinline__ float fast_tanh(float x) {
    float e = __builtin_exp2f(x * 2.8853900817779268f);  // 2*log2(e)
    return 1.0f - 2.0f / (e + 1.0f);
}

// ---------------------------------------------------------------------------
// w1 -> bf16 preconvert (one-time tiny kernel, 32768 elems)
// ---------------------------------------------------------------------------
__global__ __launch_bounds__(256) void convert_w1_kernel(const float* __restrict__ w1,
                                                         unsigned short* __restrict__ w1b) {
    int i = blockIdx.x * 256 + threadIdx.x;
    if (i * 4 >= HID * IN_DIM) return;
    float4 v = *(const float4*)&w1[i * 4];
    ushort4 r;
    r.x = f2bf(v.x); r.y = f2bf(v.y); r.z = f2bf(v.z); r.w = f2bf(v.w);
    *(ushort4*)&w1b[i * 4] = r;
}

// ---------------------------------------------------------------------------
// 1) Partition: bucket-group edges by dst>>8 via LDS counting sort with
//    PACKED 4B staging (16 KB). S1_CHUNK=4096 -> 391 blocks, ~24 KB LDS ->
//    4 blocks/CU (round-9's 196 blocks left 60 CUs idle).
//    Copy-out recovers the bucket of slot i by binary search over base[].
// ---------------------------------------------------------------------------
__global__ __launch_bounds__(512) void partition_kernel(const int* __restrict__ src,
                                                        const int* __restrict__ dst,
                                                        int* __restrict__ gcur,
                                                        int* __restrict__ ebuf) {
    __shared__ int hist[NBKT];
    __shared__ int base[NBKT];
    __shared__ int gpos[NBKT];
    __shared__ int cur[NBKT];
    __shared__ int seg[512];
    __shared__ int staged[S1_CHUNK];   // 16 KB packed words

    int t = threadIdx.x;
    if (t < NBKT) hist[t] = 0;
    __syncthreads();

    int base4 = blockIdx.x * (S1_CHUNK / 4);     // int4 index into src/dst
    int rem4  = N_EDGES / 4 - base4;

    int4 sv[2], dv[2];
#pragma unroll
    for (int j = 0; j < 2; j++) {
        int i4 = j * 512 + t;
        if (i4 < rem4) {
            sv[j] = *(const int4*)&src[(base4 + i4) * 4];
            dv[j] = *(const int4*)&dst[(base4 + i4) * 4];
        } else {
            dv[j] = make_int4(-1, -1, -1, -1);   // sentinel: invalid
        }
    }
#pragma unroll
    for (int j = 0; j < 2; j++) {
        if (dv[j].x >= 0) {
            atomicAdd(&hist[dv[j].x >> 8], 1);
            atomicAdd(&hist[dv[j].y >> 8], 1);
            atomicAdd(&hist[dv[j].z >> 8], 1);
            atomicAdd(&hist[dv[j].w >> 8], 1);
        }
    }
    __syncthreads();

    // block-exclusive scan over NBKT buckets (Hillis-Steele over 512)
    seg[t] = (t < NBKT) ? hist[t] : 0;
    __syncthreads();
    for (int off = 1; off < 512; off <<= 1) {
        int a = (t >= off) ? seg[t - off] : 0;
        __syncthreads();
        seg[t] += a;
        __syncthreads();
    }
    if (t < NBKT) {
        int excl = seg[t] - hist[t];
        base[t] = excl;
        cur[t]  = excl;
        if (hist[t] > 0) gpos[t] = atomicAdd(&gcur[GC(t)], hist[t]);
    }
    __syncthreads();

    // scatter register-held edges into bucket-sorted LDS staging (packed 4B)
#pragma unroll
    for (int j = 0; j < 2; j++) {
        if (dv[j].x >= 0) {
            int b, p;
            b = dv[j].x >> 8; p = atomicAdd(&cur[b], 1);
            staged[p] = ((dv[j].x & (NPB - 1)) << 17) | sv[j].x;
            b = dv[j].y >> 8; p = atomicAdd(&cur[b], 1);
            staged[p] = ((dv[j].y & (NPB - 1)) << 17) | sv[j].y;
            b = dv[j].z >> 8; p = atomicAdd(&cur[b], 1);
            staged[p] = ((dv[j].z & (NPB - 1)) << 17) | sv[j].z;
            b = dv[j].w >> 8; p = atomicAdd(&cur[b], 1);
            staged[p] = ((dv[j].w & (NPB - 1)) << 17) | sv[j].w;
        }
    }
    __syncthreads();

    // copy out: consecutive i within a bucket -> consecutive global slots.
    // bucket(i) = largest b with base[b] <= i (handles empty buckets).
    int n = N_EDGES - base4 * 4;
    if (n > S1_CHUNK) n = S1_CHUNK;
    for (int i = t; i < n; i += 512) {
        int w = staged[i];
        int lo = 0, hi = NBKT - 1;
        while (lo < hi) {
            int mid = (lo + hi + 1) >> 1;
            if (base[mid] <= i) lo = mid; else hi = mid - 1;
        }
        int off2 = gpos[lo] + (i - base[lo]);
        if (off2 < BCAP) ebuf[(size_t)lo * BCAP + off2] = w;
    }
}

// ---------------------------------------------------------------------------
// 2) Per-bucket degree count -> rs2[node] = {beg, end} (absolute, base
//    b*BCAP) + nrm.
// ---------------------------------------------------------------------------
__global__ __launch_bounds__(512) void deg_kernel(const int* __restrict__ gcur,
                                                  const int* __restrict__ ebuf,
                                                  int2* __restrict__ rs2,
                                                  float* __restrict__ nrm) {
    __shared__ int dcnt[NPB];
    __shared__ int s[NPB];
    int b = blockIdx.x;
    int t = threadIdx.x;
    if (t < NPB) dcnt[t] = 0;
    __syncthreads();

    int ecnt = gcur[GC(b)];
    if (ecnt > BCAP) ecnt = BCAP;
    for (int j = t; j < ecnt; j += 512)
        atomicAdd(&dcnt[PK_LI(ebuf[(size_t)b * BCAP + j])], 1);
    __syncthreads();

    int v = 0;
    if (t < NPB) { v = dcnt[t]; s[t] = v; }
    __syncthreads();
    for (int off = 1; off < NPB; off <<= 1) {
        int a = (t < NPB && t >= off) ? s[t - off] : 0;
        __syncthreads();
        if (t < NPB) s[t] += a;
        __syncthreads();
    }

    int nbase = b * NPB;
    int nn = N_NODES - nbase;
    if (nn > NPB) nn = NPB;
    if (t < nn) {
        int incl = s[t];
        rs2[nbase + t] = make_int2(b * BCAP + incl - v, b * BCAP + incl);  // {beg,end}
        nrm[nbase + t] = rsqrtf(fmaxf((float)v, 1.0f));
    }
}

// ---------------------------------------------------------------------------
// 3) PERSISTENT MFMA GEMM: h = relu(x @ w1^T + b1), bf16, fused gate dots.
//    Grid = 512 blocks (2/CU, all co-resident). B staged in LDS ONCE per
//    block (was once per 128-row tile = 782 stagings + block churn), then a
//    grid-stride loop over M-tiles: batch 16 x-float4 loads -> 64 MFMA ->
//    epilogue, no barriers in the loop.
// ---------------------------------------------------------------------------
#define GEMM_BLOCKS 512
__global__ __launch_bounds__(512, 4) void gemm_kernel(const float* __restrict__ x,
                                                      const unsigned short* __restrict__ w1b,
                                                      const float* __restrict__ b1,
                                                      const float* __restrict__ gw,
                                                      const float* __restrict__ nrm,
                                                      unsigned short* __restrict__ h,
                                                      float2* __restrict__ pd_pack,
                                                      float2* __restrict__ ps_pack) {
    __shared__ unsigned short Bs[HID * IN_DIM];   // 64 KB, swizzled 16B chunks

    int tid  = threadIdx.x;
    int wv   = tid >> 6;          // 0..7
    int lane = tid & 63;
    int col  = lane & 15;
    int kq   = lane >> 4;         // 0..3

    // stage B once: thread t stages row n = t>>2, chunks c = (t&3) + 4*j
    // chunk (n,c) -> byte n*512 + ((c ^ (n&7))*16): read-side conflict-free.
    {
        int n  = tid >> 2;
        int c0 = tid & 3;
        const unsigned short* srcp = &w1b[n * IN_DIM];
#pragma unroll
        for (int j = 0; j < 8; j++) {
            int c = c0 + 4 * j;
            *(ushort8*)((char*)Bs + n * 512 + ((c ^ (n & 7)) * 16)) =
                *(const ushort8*)&srcp[c * 8];
        }
    }

    float bias[8], wd[8], wsv[8];
#pragma unroll
    for (int nf = 0; nf < 8; nf++) {
        bias[nf] = b1[nf * 16 + col];
        wd[nf]   = gw[nf * 16 + col];
        wsv[nf]  = gw[HID + nf * 16 + col];
    }

    __syncthreads();   // Bs ready; no barriers after this point

    for (int bm = blockIdx.x * 128; bm < N_NODES; bm += GEMM_BLOCKS * 128) {
        int row  = bm + wv * 16 + col;
        bool rok = row < N_NODES;
        const float* ap = &x[(size_t)row * IN_DIM + kq * 8];

        // batch-load this lane's full x slice (16 float4), convert to 8 frags
        bf16x8 af[8];
#pragma unroll
        for (int i = 0; i < 8; i++) {
            float4 a0 = {0, 0, 0, 0}, a1 = {0, 0, 0, 0};
            if (rok) {
                a0 = *(const float4*)(ap + 32 * i);
                a1 = *(const float4*)(ap + 32 * i + 4);
            }
            ushort8 av;
            av[0] = f2bf(a0.x); av[1] = f2bf(a0.y); av[2] = f2bf(a0.z); av[3] = f2bf(a0.w);
            av[4] = f2bf(a1.x); av[5] = f2bf(a1.y); av[6] = f2bf(a1.z); av[7] = f2bf(a1.w);
            af[i] = *(bf16x8*)&av;
        }

        f32x4 acc[8];
#pragma unroll
        for (int nf = 0; nf < 8; nf++) acc[nf] = (f32x4){0.f, 0.f, 0.f, 0.f};

#pragma unroll
        for (int i = 0; i < 8; i++) {                 // k0 = 32*i
            int swz = (4 * i + kq) ^ (col & 7);       // chunk (k0>>3)+kq, xor row&7
#pragma unroll
            for (int nf = 0; nf < 8; nf++) {
                int n = nf * 16 + col;
                bf16x8 bfrag = *(bf16x8*)((char*)Bs + n * 512 + swz * 16);
                acc[nf] = __builtin_amdgcn_mfma_f32_16x16x32_bf16(af[i], bfrag, acc[nf], 0, 0, 0);
            }
        }

#pragma unroll
        for (int r = 0; r < 4; r++) {
            int gm = bm + wv * 16 + kq * 4 + r;   // uniform across the 16 col-lanes
            float pd = 0.f, ps = 0.f;
            bool ok = (gm < N_NODES);
#pragma unroll
            for (int nf = 0; nf < 8; nf++) {
                float v = fmaxf(acc[nf][r] + bias[nf], 0.f);
                pd = fmaf(v, wd[nf], pd);
                ps = fmaf(v, wsv[nf], ps);
                if (ok) h[(size_t)gm * HID + nf * 16 + col] = f2bf(v);
            }
#pragma unroll
            for (int m = 1; m < 16; m <<= 1) {
                pd += __shfl_xor(pd, m);
                ps += __shfl_xor(ps, m);
            }
            if (ok && col == 0) {
                float nv = nrm[gm];
                pd_pack[gm] = make_float2(pd, nv);
                ps_pack[gm] = make_float2(ps, nv);
            }
        }
    }
}

// ---------------------------------------------------------------------------
// 4) Fused sort+gate+aggregate: one 1024-thr block per 256-node bucket.
//    Phase 1: counting-sort the bucket's edges into LDS ({src, coef}),
//    gate coefficient computed inline. Phase 2: per-node register
//    aggregation, 16-deep main loop (4 edges/lane-slot -> 16 h-rows in
//    flight per wave, was 8) to push the gather queue harder.
// ---------------------------------------------------------------------------
__global__ __launch_bounds__(1024) void spagg2_kernel(const int* __restrict__ gcur,
                                                      const int* __restrict__ ebuf,
                                                      const int2* __restrict__ rs2,
                                                      const float2* __restrict__ pd_pack,
                                                      const float2* __restrict__ ps_pack,
                                                      const float* __restrict__ gb,
                                                      const unsigned short* __restrict__ h,
                                                      float* __restrict__ out) {
    __shared__ int2   sorted[BCAP];   // 44 KB {src, coef}
    __shared__ int    curs[NPB];
    __shared__ int    begs[NPB];
    __shared__ int    ends[NPB];
    __shared__ float2 pdl[NPB];

    int b = blockIdx.x;
    int t = threadIdx.x;
    int nbase = b * NPB;

    if (t < NPB) {
        int node = nbase + t;
        if (node < N_NODES) {
            int2 r = rs2[node];
            int lb = r.x - b * BCAP;
            begs[t] = lb; curs[t] = lb;
            ends[t] = r.y - b * BCAP;
            pdl[t]  = pd_pack[node];
        } else {
            begs[t] = 0; curs[t] = 0; ends[t] = 0;
            pdl[t] = make_float2(0.f, 0.f);
        }
    }
    __syncthreads();

    int ecnt = gcur[GC(b)];
    if (ecnt > BCAP) ecnt = BCAP;
    float gbv = gb[0];

    // phase 1: gate + counting-sort into LDS
    for (int j = t; j < ecnt; j += 1024) {
        int p  = ebuf[(size_t)b * BCAP + j];
        int s  = PK_SRC(p);
        int li = PK_LI(p);
        int pos = atomicAdd(&curs[li], 1);
        float2 pdp = pdl[li];               // {a_dst[d], nrm[d]}
        float2 psp = ps_pack[s];            // {a_src[s], nrm[s]}
        float g = fast_tanh(pdp.x + psp.x + gbv) * pdp.y * psp.y;
        sorted[pos] = make_int2(s, __float_as_int(g));
    }
    __syncthreads();

    // phase 2: per-node aggregation (wave w handles nodes w + 16k)
    int lane = t & 63;
    int w    = t >> 6;     // 0..15
    int q  = lane >> 4;    // 0..3: edge slot within wave
    int ql = lane & 15;    // channel group: ch = ql*8

#pragma unroll
    for (int k = 0; k < NPB / 16; k++) {
        int li = w + 16 * k;
        int node = nbase + li;
        if (node >= N_NODES) continue;
        int beg = begs[li];
        int end = ends[li];

        float acc[8];
#pragma unroll
        for (int u = 0; u < 8; u++) acc[u] = 0.f;

        int j = beg;
        for (; j + 16 <= end; j += 16) {       // 16 h-rows in flight per wave
            int2 e0 = sorted[j + q];
            int2 e1 = sorted[j + 4 + q];
            int2 e2 = sorted[j + 8 + q];
            int2 e3 = sorted[j + 12 + q];
            ushort8 r0 = *(const ushort8*)&h[(size_t)e0.x * HID + ql * 8];
            ushort8 r1 = *(const ushort8*)&h[(size_t)e1.x * HID + ql * 8];
            ushort8 r2 = *(const ushort8*)&h[(size_t)e2.x * HID + ql * 8];
            ushort8 r3 = *(const ushort8*)&h[(size_t)e3.x * HID + ql * 8];
            float c0 = __int_as_float(e0.y);
            float c1 = __int_as_float(e1.y);
            float c2 = __int_as_float(e2.y);
            float c3 = __int_as_float(e3.y);
#pragma unroll
            for (int u = 0; u < 8; u++) {
                acc[u] = fmaf(c0, bf2f(r0[u]), acc[u]);
                acc[u] = fmaf(c1, bf2f(r1[u]), acc[u]);
                acc[u] = fmaf(c2, bf2f(r2[u]), acc[u]);
                acc[u] = fmaf(c3, bf2f(r3[u]), acc[u]);
            }
        }
        for (; j + 8 <= end; j += 8) {
            int2 e0 = sorted[j + q];
            int2 e1 = sorted[j + 4 + q];
            ushort8 r0 = *(const ushort8*)&h[(size_t)e0.x * HID + ql * 8];
            ushort8 r1 = *(const ushort8*)&h[(size_t)e1.x * HID + ql * 8];
            float c0 = __int_as_float(e0.y);
            float c1 = __int_as_float(e1.y);
#pragma unroll
            for (int u = 0; u < 8; u++) {
                acc[u] = fmaf(c0, bf2f(r0[u]), acc[u]);
                acc[u] = fmaf(c1, bf2f(r1[u]), acc[u]);
            }
        }
        for (; j < end; j += 4) {
            bool act = (j + q) < end;
            int idx = act ? (j + q) : beg;      // beg valid: j<end => beg<end
            int2 e = sorted[idx];
            ushort8 r = *(const ushort8*)&h[(size_t)e.x * HID + ql * 8];
            float c = act ? __int_as_float(e.y) : 0.f;
#pragma unroll
            for (int u = 0; u < 8; u++) acc[u] = fmaf(c, bf2f(r[u]), acc[u]);
        }
        // combine the 4 edge-slots (lane bits 4,5)
#pragma unroll
        for (int u = 0; u < 8; u++) {
            acc[u] += __shfl_xor(acc[u], 16);
            acc[u] += __shfl_xor(acc[u], 32);
        }
        if (q == 0) {
            ushort8 hd = *(const ushort8*)&h[(size_t)node * HID + ql * 8];
            f32x4 o0, o1;
            o0.x = fmaf(EPS_C, bf2f(hd[0]), acc[0]);
            o0.y = fmaf(EPS_C, bf2f(hd[1]), acc[1]);
            o0.z = fmaf(EPS_C, bf2f(hd[2]), acc[2]);
            o0.w = fmaf(EPS_C, bf2f(hd[3]), acc[3]);
            o1.x = fmaf(EPS_C, bf2f(hd[4]), acc[4]);
            o1.y = fmaf(EPS_C, bf2f(hd[5]), acc[5]);
            o1.z = fmaf(EPS_C, bf2f(hd[6]), acc[6]);
            o1.w = fmaf(EPS_C, bf2f(hd[7]), acc[7]);
            __builtin_nontemporal_store(o0, (f32x4*)&out[(size_t)node * HID + ql * 8]);
            __builtin_nontemporal_store(o1, (f32x4*)&out[(size_t)node * HID + ql * 8 + 4]);
        }
    }
}

// ---------------------------------------------------------------------------
extern "C" void kernel_launch(void* const* d_in, const int* in_sizes, int n_in,
                              void* d_out, int out_size, void* d_ws, size_t ws_size,
                              hipStream_t stream) {
    const float* x  = (const float*)d_in[0];
    const int*   ei = (const int*)d_in[1];
    const float* w1 = (const float*)d_in[2];
    const float* b1 = (const float*)d_in[3];
    const float* gw = (const float*)d_in[4];
    const float* gb = (const float*)d_in[5];
    float* out = (float*)d_out;

    const int* src = ei;
    const int* dst = ei + N_EDGES;

    uintptr_t base = (uintptr_t)d_ws;
    size_t off = 0;
    auto alloc = [&](size_t bytes) -> void* {
        void* p = (void*)(base + off);
        off += (bytes + 255) & ~(size_t)255;
        return p;
    };
    unsigned short* h   = (unsigned short*)alloc((size_t)N_NODES * HID * 2);  // 25.6 MB
    float2* pd_pack     = (float2*)alloc((size_t)N_NODES * 8);
    float2* ps_pack     = (float2*)alloc((size_t)N_NODES * 8);
    float*  nrm         = (float*)alloc((size_t)N_NODES * 4);
    int2*   rs2         = (int2*)alloc((size_t)N_NODES * 8);
    unsigned short* w1b = (unsigned short*)alloc((size_t)HID * IN_DIM * 2);
    int*    gcur        = (int*)alloc((size_t)NBKT * 16 * 4);                 // 64B-padded
    int*    ebuf        = (int*)alloc((size_t)NBKT * BCAP * 4);               // 8.6 MB

    (void)hipMemsetAsync(gcur, 0, (size_t)NBKT * 16 * 4, stream);

    convert_w1_kernel<<<(HID * IN_DIM / 4 + 255) / 256, 256, 0, stream>>>(w1, w1b);
    partition_kernel<<<S1_BLOCKS, 512, 0, stream>>>(src, dst, gcur, ebuf);
    deg_kernel<<<NBKT, 512, 0, stream>>>(gcur, ebuf, rs2, nrm);
    gemm_kernel<<<GEMM_BLOCKS, 512, 0, stream>>>(x, w1b, b1, gw, nrm,
                                                 h, pd_pack, ps_pack);
    spagg2_kernel<<<NBKT, 1024, 0, stream>>>(gcur, ebuf, rs2,
                                             pd_pack, ps_pack, gb, h, out);
}

// Round 11
// 287.546 us; speedup vs baseline: 1.4776x; 1.4776x over previous
//
#include <hip/hip_runtime.h>
#include <math.h>
#include <stdint.h>

#define N_NODES 100000
#define N_EDGES 1600000
#define IN_DIM  256
#define HID     128
#define EPS_C   0.3f

// bucket partition for write-local CSR processing
#define NPB      256              // nodes per bucket (dst >> 8)
#define NBKT     391              // ceil(N_NODES / NPB)
#define BCAP     5504             // per-bucket edge capacity (mean 4096, +22 sigma)
#define S1_CHUNK 4096             // edges per partition block (391 blocks)
#define S1_BLOCKS 391             // ceil(N_EDGES / S1_CHUNK)
#define GC(b)    ((b) * 16)       // gcur padded: 1 counter per 64B line

// packed edge word: bits [16:0] = src (100000 < 2^17), bits [24:17] = dst & 255
#define PK_SRC(p)  ((p) & 0x1FFFF)
#define PK_LI(p)   ((p) >> 17)

typedef __attribute__((ext_vector_type(8))) __bf16 bf16x8;
typedef __attribute__((ext_vector_type(4))) float  f32x4;
typedef __attribute__((ext_vector_type(8))) unsigned short ushort8;

static __device__ __forceinline__ unsigned short f2bf(float f) {
    unsigned u = __float_as_uint(f);
    unsigned r = (u + 0x7fffu + ((u >> 16) & 1u)) >> 16;
    return (unsigned short)r;
}
static __device__ __forceinline__ float bf2f(unsigned short s) {
    return __uint_as_float((unsigned)s << 16);
}
// branch-free tanh: 1 - 2/(exp2(2x*log2e)+1); correct limits at +-inf
static __device__ __forceinline__ float fast_tanh(float x) {
    float e = __builtin_exp2f(x * 2.8853900817779268f);  // 2*log2(e)
    return 1.0f - 2.0f / (e + 1.0f);
}

// ---------------------------------------------------------------------------
// w1 -> bf16 preconvert (one-time tiny kernel, 32768 elems)
// ---------------------------------------------------------------------------
__global__ __launch_bounds__(256) void convert_w1_kernel(const float* __restrict__ w1,
                                                         unsigned short* __restrict__ w1b) {
    int i = blockIdx.x * 256 + threadIdx.x;
    if (i * 4 >= HID * IN_DIM) return;
    float4 v = *(const float4*)&w1[i * 4];
    ushort4 r;
    r.x = f2bf(v.x); r.y = f2bf(v.y); r.z = f2bf(v.z); r.w = f2bf(v.w);
    *(ushort4*)&w1b[i * 4] = r;
}

// ---------------------------------------------------------------------------
// 1) Partition: bucket-group edges by dst>>8 via LDS counting sort with
//    PACKED 4B staging (16 KB). 391 blocks, ~24 KB LDS -> 4 blocks/CU.
//    Copy-out recovers the bucket of slot i by binary search over base[].
// ---------------------------------------------------------------------------
__global__ __launch_bounds__(512) void partition_kernel(const int* __restrict__ src,
                                                        const int* __restrict__ dst,
                                                        int* __restrict__ gcur,
                                                        int* __restrict__ ebuf) {
    __shared__ int hist[NBKT];
    __shared__ int base[NBKT];
    __shared__ int gpos[NBKT];
    __shared__ int cur[NBKT];
    __shared__ int seg[512];
    __shared__ int staged[S1_CHUNK];   // 16 KB packed words

    int t = threadIdx.x;
    if (t < NBKT) hist[t] = 0;
    __syncthreads();

    int base4 = blockIdx.x * (S1_CHUNK / 4);     // int4 index into src/dst
    int rem4  = N_EDGES / 4 - base4;

    int4 sv[2], dv[2];
#pragma unroll
    for (int j = 0; j < 2; j++) {
        int i4 = j * 512 + t;
        if (i4 < rem4) {
            sv[j] = *(const int4*)&src[(base4 + i4) * 4];
            dv[j] = *(const int4*)&dst[(base4 + i4) * 4];
        } else {
            dv[j] = make_int4(-1, -1, -1, -1);   // sentinel: invalid
        }
    }
#pragma unroll
    for (int j = 0; j < 2; j++) {
        if (dv[j].x >= 0) {
            atomicAdd(&hist[dv[j].x >> 8], 1);
            atomicAdd(&hist[dv[j].y >> 8], 1);
            atomicAdd(&hist[dv[j].z >> 8], 1);
            atomicAdd(&hist[dv[j].w >> 8], 1);
        }
    }
    __syncthreads();

    // block-exclusive scan over NBKT buckets (Hillis-Steele over 512)
    seg[t] = (t < NBKT) ? hist[t] : 0;
    __syncthreads();
    for (int off = 1; off < 512; off <<= 1) {
        int a = (t >= off) ? seg[t - off] : 0;
        __syncthreads();
        seg[t] += a;
        __syncthreads();
    }
    if (t < NBKT) {
        int excl = seg[t] - hist[t];
        base[t] = excl;
        cur[t]  = excl;
        if (hist[t] > 0) gpos[t] = atomicAdd(&gcur[GC(t)], hist[t]);
    }
    __syncthreads();

    // scatter register-held edges into bucket-sorted LDS staging (packed 4B)
#pragma unroll
    for (int j = 0; j < 2; j++) {
        if (dv[j].x >= 0) {
            int b, p;
            b = dv[j].x >> 8; p = atomicAdd(&cur[b], 1);
            staged[p] = ((dv[j].x & (NPB - 1)) << 17) | sv[j].x;
            b = dv[j].y >> 8; p = atomicAdd(&cur[b], 1);
            staged[p] = ((dv[j].y & (NPB - 1)) << 17) | sv[j].y;
            b = dv[j].z >> 8; p = atomicAdd(&cur[b], 1);
            staged[p] = ((dv[j].z & (NPB - 1)) << 17) | sv[j].z;
            b = dv[j].w >> 8; p = atomicAdd(&cur[b], 1);
            staged[p] = ((dv[j].w & (NPB - 1)) << 17) | sv[j].w;
        }
    }
    __syncthreads();

    // copy out: consecutive i within a bucket -> consecutive global slots.
    // bucket(i) = largest b with base[b] <= i (handles empty buckets).
    int n = N_EDGES - base4 * 4;
    if (n > S1_CHUNK) n = S1_CHUNK;
    for (int i = t; i < n; i += 512) {
        int w = staged[i];
        int lo = 0, hi = NBKT - 1;
        while (lo < hi) {
            int mid = (lo + hi + 1) >> 1;
            if (base[mid] <= i) lo = mid; else hi = mid - 1;
        }
        int off2 = gpos[lo] + (i - base[lo]);
        if (off2 < BCAP) ebuf[(size_t)lo * BCAP + off2] = w;
    }
}

// ---------------------------------------------------------------------------
// 2) Per-bucket degree count -> rs2[node] = {beg, end} (absolute, base
//    b*BCAP) + nrm.
// ---------------------------------------------------------------------------
__global__ __launch_bounds__(512) void deg_kernel(const int* __restrict__ gcur,
                                                  const int* __restrict__ ebuf,
                                                  int2* __restrict__ rs2,
                                                  float* __restrict__ nrm) {
    __shared__ int dcnt[NPB];
    __shared__ int s[NPB];
    int b = blockIdx.x;
    int t = threadIdx.x;
    if (t < NPB) dcnt[t] = 0;
    __syncthreads();

    int ecnt = gcur[GC(b)];
    if (ecnt > BCAP) ecnt = BCAP;
    for (int j = t; j < ecnt; j += 512)
        atomicAdd(&dcnt[PK_LI(ebuf[(size_t)b * BCAP + j])], 1);
    __syncthreads();

    int v = 0;
    if (t < NPB) { v = dcnt[t]; s[t] = v; }
    __syncthreads();
    for (int off = 1; off < NPB; off <<= 1) {
        int a = (t < NPB && t >= off) ? s[t - off] : 0;
        __syncthreads();
        if (t < NPB) s[t] += a;
        __syncthreads();
    }

    int nbase = b * NPB;
    int nn = N_NODES - nbase;
    if (nn > NPB) nn = NPB;
    if (t < nn) {
        int incl = s[t];
        rs2[nbase + t] = make_int2(b * BCAP + incl - v, b * BCAP + incl);  // {beg,end}
        nrm[nbase + t] = rsqrtf(fmaxf((float)v, 1.0f));
    }
}

// ---------------------------------------------------------------------------
// 3) MFMA GEMM: h = relu(x @ w1^T + b1), bf16, fused gate dots.
//    Per-tile blocks (782), barrier-free k-loop, w1b in LDS (swizzled).
//    KEY CHANGE vs all prior ~67us variants: x loads are held as 16 RAW
//    float4 registers and pinned as one VMEM_READ cluster via
//    sched_group_barrier -- prior variants let the compiler serialize to
//    2-3 loads in flight (VGPR 52-64), making the kernel latency-bound.
//    Conversions happen inside the MFMA loop under fine-grained vmcnt.
// ---------------------------------------------------------------------------
__global__ __launch_bounds__(512, 4) void gemm_kernel(const float* __restrict__ x,
                                                      const unsigned short* __restrict__ w1b,
                                                      const float* __restrict__ b1,
                                                      const float* __restrict__ gw,
                                                      const float* __restrict__ nrm,
                                                      unsigned short* __restrict__ h,
                                                      float2* __restrict__ pd_pack,
                                                      float2* __restrict__ ps_pack) {
    __shared__ unsigned short Bs[HID * IN_DIM];   // 64 KB, swizzled 16B chunks

    int tid  = threadIdx.x;
    int bm   = blockIdx.x * 128;
    int wv   = tid >> 6;          // 0..7
    int lane = tid & 63;
    int col  = lane & 15;
    int kq   = lane >> 4;         // 0..3

    int row  = bm + wv * 16 + col;
    bool rok = row < N_NODES;
    const float* ap = &x[(size_t)row * IN_DIM + kq * 8];

    // issue ALL 16 x-float4 loads first, keep raw (64 VGPR), cluster them
    float4 ar[16];
#pragma unroll
    for (int i = 0; i < 8; i++) {
        float4 a0 = {0, 0, 0, 0}, a1 = {0, 0, 0, 0};
        if (rok) {
            a0 = *(const float4*)(ap + 32 * i);
            a1 = *(const float4*)(ap + 32 * i + 4);
        }
        ar[2 * i]     = a0;
        ar[2 * i + 1] = a1;
    }
    // pin the 16 VMEM reads as one issue cluster (0x20 = VMEM_READ)
    __builtin_amdgcn_sched_group_barrier(0x20, 16, 0);

    // stage B: thread t stages row n = t>>2, chunks c = (t&3) + 4*j;
    // chunk (n,c) -> byte n*512 + ((c ^ (n&7))*16): read-side conflict-free.
    {
        int n  = tid >> 2;
        int c0 = tid & 3;
        const unsigned short* srcp = &w1b[n * IN_DIM];
#pragma unroll
        for (int j = 0; j < 8; j++) {
            int c = c0 + 4 * j;
            *(ushort8*)((char*)Bs + n * 512 + ((c ^ (n & 7)) * 16)) =
                *(const ushort8*)&srcp[c * 8];
        }
    }

    f32x4 acc[8];
#pragma unroll
    for (int nf = 0; nf < 8; nf++) acc[nf] = (f32x4){0.f, 0.f, 0.f, 0.f};

    __syncthreads();   // Bs ready; no barriers after this point

#pragma unroll
    for (int i = 0; i < 8; i++) {                 // k0 = 32*i
        float4 a0 = ar[2 * i], a1 = ar[2 * i + 1];
        ushort8 av;
        av[0] = f2bf(a0.x); av[1] = f2bf(a0.y); av[2] = f2bf(a0.z); av[3] = f2bf(a0.w);
        av[4] = f2bf(a1.x); av[5] = f2bf(a1.y); av[6] = f2bf(a1.z); av[7] = f2bf(a1.w);
        bf16x8 afrag = *(bf16x8*)&av;

        int swz = (4 * i + kq) ^ (col & 7);       // chunk (k0>>3)+kq, xor row&7
#pragma unroll
        for (int nf = 0; nf < 8; nf++) {
            int n = nf * 16 + col;
            bf16x8 bfrag = *(bf16x8*)((char*)Bs + n * 512 + swz * 16);
            acc[nf] = __builtin_amdgcn_mfma_f32_16x16x32_bf16(afrag, bfrag, acc[nf], 0, 0, 0);
        }
    }

    float bias[8], wd[8], wsv[8];
#pragma unroll
    for (int nf = 0; nf < 8; nf++) {
        bias[nf] = b1[nf * 16 + col];
        wd[nf]   = gw[nf * 16 + col];
        wsv[nf]  = gw[HID + nf * 16 + col];
    }
#pragma unroll
    for (int r = 0; r < 4; r++) {
        int gm = bm + wv * 16 + kq * 4 + r;   // uniform across the 16 col-lanes
        float pd = 0.f, ps = 0.f;
        bool ok = (gm < N_NODES);
#pragma unroll
        for (int nf = 0; nf < 8; nf++) {
            float v = fmaxf(acc[nf][r] + bias[nf], 0.f);
            pd = fmaf(v, wd[nf], pd);
            ps = fmaf(v, wsv[nf], ps);
            if (ok) h[(size_t)gm * HID + nf * 16 + col] = f2bf(v);
        }
#pragma unroll
        for (int m = 1; m < 16; m <<= 1) {
            pd += __shfl_xor(pd, m);
            ps += __shfl_xor(ps, m);
        }
        if (ok && col == 0) {
            float nv = nrm[gm];
            pd_pack[gm] = make_float2(pd, nv);
            ps_pack[gm] = make_float2(ps, nv);
        }
    }
}

// ---------------------------------------------------------------------------
// 4) Fused sort+gate+aggregate: one 1024-thr block per 256-node bucket.
//    Phase 1: counting-sort the bucket's edges into LDS ({src, coef}),
//    gate coefficient computed inline. Phase 2: per-node register
//    aggregation, 16-deep main loop (16 h-rows in flight per wave).
// ---------------------------------------------------------------------------
__global__ __launch_bounds__(1024) void spagg2_kernel(const int* __restrict__ gcur,
                                                      const int* __restrict__ ebuf,
                                                      const int2* __restrict__ rs2,
                                                      const float2* __restrict__ pd_pack,
                                                      const float2* __restrict__ ps_pack,
                                                      const float* __restrict__ gb,
                                                      const unsigned short* __restrict__ h,
                                                      float* __restrict__ out) {
    __shared__ int2   sorted[BCAP];   // 44 KB {src, coef}
    __shared__ int    curs[NPB];
    __shared__ int    begs[NPB];
    __shared__ int    ends[NPB];
    __shared__ float2 pdl[NPB];

    int b = blockIdx.x;
    int t = threadIdx.x;
    int nbase = b * NPB;

    if (t < NPB) {
        int node = nbase + t;
        if (node < N_NODES) {
            int2 r = rs2[node];
            int lb = r.x - b * BCAP;
            begs[t] = lb; curs[t] = lb;
            ends[t] = r.y - b * BCAP;
            pdl[t]  = pd_pack[node];
        } else {
            begs[t] = 0; curs[t] = 0; ends[t] = 0;
            pdl[t] = make_float2(0.f, 0.f);
        }
    }
    __syncthreads();

    int ecnt = gcur[GC(b)];
    if (ecnt > BCAP) ecnt = BCAP;
    float gbv = gb[0];

    // phase 1: gate + counting-sort into LDS
    for (int j = t; j < ecnt; j += 1024) {
        int p  = ebuf[(size_t)b * BCAP + j];
        int s  = PK_SRC(p);
        int li = PK_LI(p);
        int pos = atomicAdd(&curs[li], 1);
        float2 pdp = pdl[li];               // {a_dst[d], nrm[d]}
        float2 psp = ps_pack[s];            // {a_src[s], nrm[s]}
        float g = fast_tanh(pdp.x + psp.x + gbv) * pdp.y * psp.y;
        sorted[pos] = make_int2(s, __float_as_int(g));
    }
    __syncthreads();

    // phase 2: per-node aggregation (wave w handles nodes w + 16k)
    int lane = t & 63;
    int w    = t >> 6;     // 0..15
    int q  = lane >> 4;    // 0..3: edge slot within wave
    int ql = lane & 15;    // channel group: ch = ql*8

#pragma unroll
    for (int k = 0; k < NPB / 16; k++) {
        int li = w + 16 * k;
        int node = nbase + li;
        if (node >= N_NODES) continue;
        int beg = begs[li];
        int end = ends[li];

        float acc[8];
#pragma unroll
        for (int u = 0; u < 8; u++) acc[u] = 0.f;

        int j = beg;
        for (; j + 16 <= end; j += 16) {       // 16 h-rows in flight per wave
            int2 e0 = sorted[j + q];
            int2 e1 = sorted[j + 4 + q];
            int2 e2 = sorted[j + 8 + q];
            int2 e3 = sorted[j + 12 + q];
            ushort8 r0 = *(const ushort8*)&h[(size_t)e0.x * HID + ql * 8];
            ushort8 r1 = *(const ushort8*)&h[(size_t)e1.x * HID + ql * 8];
            ushort8 r2 = *(const ushort8*)&h[(size_t)e2.x * HID + ql * 8];
            ushort8 r3 = *(const ushort8*)&h[(size_t)e3.x * HID + ql * 8];
            float c0 = __int_as_float(e0.y);
            float c1 = __int_as_float(e1.y);
            float c2 = __int_as_float(e2.y);
            float c3 = __int_as_float(e3.y);
#pragma unroll
            for (int u = 0; u < 8; u++) {
                acc[u] = fmaf(c0, bf2f(r0[u]), acc[u]);
                acc[u] = fmaf(c1, bf2f(r1[u]), acc[u]);
                acc[u] = fmaf(c2, bf2f(r2[u]), acc[u]);
                acc[u] = fmaf(c3, bf2f(r3[u]), acc[u]);
            }
        }
        for (; j + 8 <= end; j += 8) {
            int2 e0 = sorted[j + q];
            int2 e1 = sorted[j + 4 + q];
            ushort8 r0 = *(const ushort8*)&h[(size_t)e0.x * HID + ql * 8];
            ushort8 r1 = *(const ushort8*)&h[(size_t)e1.x * HID + ql * 8];
            float c0 = __int_as_float(e0.y);
            float c1 = __int_as_float(e1.y);
#pragma unroll
            for (int u = 0; u < 8; u++) {
                acc[u] = fmaf(c0, bf2f(r0[u]), acc[u]);
                acc[u] = fmaf(c1, bf2f(r1[u]), acc[u]);
            }
        }
        for (; j < end; j += 4) {
            bool act = (j + q) < end;
            int idx = act ? (j + q) : beg;      // beg valid: j<end => beg<end
            int2 e = sorted[idx];
            ushort8 r = *(const ushort8*)&h[(size_t)e.x * HID + ql * 8];
            float c = act ? __int_as_float(e.y) : 0.f;
#pragma unroll
            for (int u = 0; u < 8; u++) acc[u] = fmaf(c, bf2f(r[u]), acc[u]);
        }
        // combine the 4 edge-slots (lane bits 4,5)
#pragma unroll
        for (int u = 0; u < 8; u++) {
            acc[u] += __shfl_xor(acc[u], 16);
            acc[u] += __shfl_xor(acc[u], 32);
        }
        if (q == 0) {
            ushort8 hd = *(const ushort8*)&h[(size_t)node * HID + ql * 8];
            f32x4 o0, o1;
            o0.x = fmaf(EPS_C, bf2f(hd[0]), acc[0]);
            o0.y = fmaf(EPS_C, bf2f(hd[1]), acc[1]);
            o0.z = fmaf(EPS_C, bf2f(hd[2]), acc[2]);
            o0.w = fmaf(EPS_C, bf2f(hd[3]), acc[3]);
            o1.x = fmaf(EPS_C, bf2f(hd[4]), acc[4]);
            o1.y = fmaf(EPS_C, bf2f(hd[5]), acc[5]);
            o1.z = fmaf(EPS_C, bf2f(hd[6]), acc[6]);
            o1.w = fmaf(EPS_C, bf2f(hd[7]), acc[7]);
            __builtin_nontemporal_store(o0, (f32x4*)&out[(size_t)node * HID + ql * 8]);
            __builtin_nontemporal_store(o1, (f32x4*)&out[(size_t)node * HID + ql * 8 + 4]);
        }
    }
}

// ---------------------------------------------------------------------------
extern "C" void kernel_launch(void* const* d_in, const int* in_sizes, int n_in,
                              void* d_out, int out_size, void* d_ws, size_t ws_size,
                              hipStream_t stream) {
    const float* x  = (const float*)d_in[0];
    const int*   ei = (const int*)d_in[1];
    const float* w1 = (const float*)d_in[2];
    const float* b1 = (const float*)d_in[3];
    const float* gw = (const float*)d_in[4];
    const float* gb = (const float*)d_in[5];
    float* out = (float*)d_out;

    const int* src = ei;
    const int* dst = ei + N_EDGES;

    uintptr_t base = (uintptr_t)d_ws;
    size_t off = 0;
    auto alloc = [&](size_t bytes) -> void* {
        void* p = (void*)(base + off);
        off += (bytes + 255) & ~(size_t)255;
        return p;
    };
    unsigned short* h   = (unsigned short*)alloc((size_t)N_NODES * HID * 2);  // 25.6 MB
    float2* pd_pack     = (float2*)alloc((size_t)N_NODES * 8);
    float2* ps_pack     = (float2*)alloc((size_t)N_NODES * 8);
    float*  nrm         = (float*)alloc((size_t)N_NODES * 4);
    int2*   rs2         = (int2*)alloc((size_t)N_NODES * 8);
    unsigned short* w1b = (unsigned short*)alloc((size_t)HID * IN_DIM * 2);
    int*    gcur        = (int*)alloc((size_t)NBKT * 16 * 4);                 // 64B-padded
    int*    ebuf        = (int*)alloc((size_t)NBKT * BCAP * 4);               // 8.6 MB

    (void)hipMemsetAsync(gcur, 0, (size_t)NBKT * 16 * 4, stream);

    convert_w1_kernel<<<(HID * IN_DIM / 4 + 255) / 256, 256, 0, stream>>>(w1, w1b);
    partition_kernel<<<S1_BLOCKS, 512, 0, stream>>>(src, dst, gcur, ebuf);
    deg_kernel<<<NBKT, 512, 0, stream>>>(gcur, ebuf, rs2, nrm);
    gemm_kernel<<<(N_NODES + 127) / 128, 512, 0, stream>>>(x, w1b, b1, gw, nrm,
                                                           h, pd_pack, ps_pack);
    spagg2_kernel<<<NBKT, 1024, 0, stream>>>(gcur, ebuf, rs2,
                                             pd_pack, ps_pack, gb, h, out);
}